// Round 1
// baseline (1680.659 us; speedup 1.0000x reference)
//
#include <hip/hip_runtime.h>

// SGLayerEpilogue: noise-add -> LeakyReLU(0.2) -> PixelNorm(over C) ->
// InstanceNorm(over HW) -> StyleMod(linear scale/shift)
// B=16, C=512, H=W=64, S=512. All fp32.
//
// Fused single-launch producer/consumer version.
//  - Producers (first 1280 tickets): style-GEMM partials (16/b) + per-pixel
//    channel reductions (64/b), grouped by batch b; publish rbuf/sp and
//    release-increment cnt[b].
//  - Consumers (next 8192 tickets): one (b,c) plane each; spin on
//    cnt[b]==80, acquire-fence, then InstanceNorm+StyleMod with z kept in
//    registers; nontemporal out stores.
// Ticket-based role assignment is deadlock-free: any running consumer
// implies all 1280 producers already started, and producers never wait.

#define BB 16
#define CC 512
#define HWN 4096          // H*W
#define HW4 1024          // HW / 4 (float4 units)
#define NSTYLE_PER_B 16   // 4 jgroup x 4 kchunk
#define NPIX_PER_B 64     // 64 px per task, 64 tasks per b
#define NPROD_PER_B 80
#define NPROD (BB * NPROD_PER_B)   // 1280
#define NCONS (BB * CC)            // 8192

#define EPS_PIXEL 1e-8f
#define EPS_INST 1e-5f

typedef float vf4 __attribute__((ext_vector_type(4)));

// Zero cnt[0..15] + ticket (idx 16); ws is poisoned by the harness reset.
__global__ void k0_init(unsigned* __restrict__ flags) {
    flags[threadIdx.x] = 0u;
}

__global__ __launch_bounds__(256) void fused(
        const float* __restrict__ x,
        const float* __restrict__ noise,
        const float* __restrict__ nw,
        const float* __restrict__ style,
        const float* __restrict__ lin_W,
        const float* __restrict__ lin_b,
        float* __restrict__ sp,
        float* __restrict__ rbuf,
        unsigned* __restrict__ cnt,
        unsigned* __restrict__ tick,
        float* __restrict__ out) {
    const int t = threadIdx.x;
    __shared__ float smem[768];
    __shared__ unsigned sq;
    if (t == 0)
        sq = __hip_atomic_fetch_add(tick, 1u, __ATOMIC_RELAXED,
                                    __HIP_MEMORY_SCOPE_AGENT);
    __syncthreads();
    const unsigned q = sq;

    if (q < NPROD) {
        // ------------------------- producer -------------------------
        const int b = (int)(q / NPROD_PER_B);
        const int r = (int)(q - (unsigned)(b * NPROD_PER_B));

        if (r < NSTYLE_PER_B) {
            // ---- style GEMM partial ----
            // sp[(b*4+z)*1024 + j] = (z==0 ? lin_b[j] : 0)
            //                        + sum_{k in chunk z} style[b,k]*lin_W[k,j]
            const int z  = r & 3;        // k chunk (128 rows)
            const int jg = r >> 2;       // j group (256 cols)
            const int j  = jg * 256 + t;
            float* ssty = smem;
            if (t < 128) ssty[t] = style[b * 512 + z * 128 + t];
            __syncthreads();
            float acc = (z == 0) ? lin_b[j] : 0.0f;
            const float* Wp = lin_W + (size_t)(z * 128) * 1024 + j;
#pragma unroll 8
            for (int k = 0; k < 128; ++k)
                acc = fmaf(ssty[k], Wp[(size_t)k * 1024], acc);
            sp[(size_t)(b * 4 + z) * 1024 + j] = acc;
        } else {
            // ---- per-pixel channel reduction -> rbuf ----
            const int pc  = r - NSTYLE_PER_B;  // 0..63
            const int hw0 = pc * 64;
            const int p   = t & 63;            // pixel within chunk
            const int g   = t >> 6;            // channel group (128 ch)
            float* snw = smem;                 // [512]
            float* red = smem + 512;           // [256]
            snw[t] = nw[t];
            snw[t + 256] = nw[t + 256];
            __syncthreads();
            const float nz = noise[b * HWN + hw0 + p];
            const float* xp = x + ((size_t)(b * CC + g * 128) * HWN) + hw0 + p;
            float acc = 0.0f;
#pragma unroll 8
            for (int k = 0; k < 128; ++k) {
                float v = xp[(size_t)k * HWN];
                float w = snw[g * 128 + k];
                float y = fmaf(w, nz, v);
                y = fmaxf(y, 0.2f * y);
                acc = fmaf(y, y, acc);
            }
            red[t] = acc;
            __syncthreads();
            if (t < 64) {
                float s = red[t] + red[t + 64] + red[t + 128] + red[t + 192];
                rbuf[b * HWN + hw0 + t] =
                    rsqrtf(fmaf(s, 1.0f / (float)CC, EPS_PIXEL));
            }
        }
        // Publish: barrier drains this block's stores into this XCD's L2
        // (compiler emits vmcnt(0) before s_barrier); leader writes back L2
        // and release-increments the batch counter at device scope.
        __syncthreads();
        if (t == 0) {
            __threadfence();
            __hip_atomic_fetch_add(&cnt[b], 1u, __ATOMIC_RELEASE,
                                   __HIP_MEMORY_SCOPE_AGENT);
        }
        return;
    }

    // --------------------------- consumer ---------------------------
    const unsigned u = q - NPROD;
    if (u >= NCONS) return;        // rocprof kernel-replay safety
    const int b = (int)(u >> 9);
    const int c = (int)(u & 511);

    // Wait until all 80 producer tasks for batch b have published.
    // Relaxed polls (coherent loads, no cache-invalidate thrash); one
    // acquire fence per thread after success so rbuf/sp reads see fresh data
    // (per-XCD L2s are not cross-coherent; no kernel boundary to flush).
    while (__hip_atomic_load(&cnt[b], __ATOMIC_RELAXED,
                             __HIP_MEMORY_SCOPE_AGENT) < NPROD_PER_B)
        __builtin_amdgcn_s_sleep(2);
    __threadfence();

    const float w = nw[c];

    // Leader prefetches style partials early to hide L2 latency.
    float s0p = 0.f, s1p = 0.f;
    if (t == 0) {
#pragma unroll
        for (int z = 0; z < 4; ++z) {
            s0p += sp[(size_t)(b * 4 + z) * 1024 + c];
            s1p += sp[(size_t)(b * 4 + z) * 1024 + 512 + c];
        }
    }

    const float4* x4 = (const float4*)x + (size_t)(b * CC + c) * HW4;
    const float4* n4 = (const float4*)noise + (size_t)b * HW4;
    const float4* r4 = (const float4*)rbuf + (size_t)b * HW4;

    float4 zv[4];
    float sum = 0.f, sum2 = 0.f;
#pragma unroll
    for (int i = 0; i < 4; ++i) {
        const int qq = t + 256 * i;
        float4 v = x4[qq];
        float4 nz = n4[qq];
        float4 rr = r4[qq];
        float y0 = fmaf(w, nz.x, v.x); y0 = fmaxf(y0, 0.2f * y0);
        float y1 = fmaf(w, nz.y, v.y); y1 = fmaxf(y1, 0.2f * y1);
        float y2 = fmaf(w, nz.z, v.z); y2 = fmaxf(y2, 0.2f * y2);
        float y3 = fmaf(w, nz.w, v.w); y3 = fmaxf(y3, 0.2f * y3);
        float4 zz;
        zz.x = y0 * rr.x; zz.y = y1 * rr.y; zz.z = y2 * rr.z; zz.w = y3 * rr.w;
        zv[i] = zz;
        sum  += zz.x + zz.y + zz.z + zz.w;
        sum2 = fmaf(zz.x, zz.x, sum2);
        sum2 = fmaf(zz.y, zz.y, sum2);
        sum2 = fmaf(zz.z, zz.z, sum2);
        sum2 = fmaf(zz.w, zz.w, sum2);
    }

    // block reduce (4 waves of 64); reuse smem[0..15]
    float* lds = smem;
#pragma unroll
    for (int off = 32; off > 0; off >>= 1) {
        sum  += __shfl_down(sum, off, 64);
        sum2 += __shfl_down(sum2, off, 64);
    }
    const int lane = t & 63, wv = t >> 6;
    if (lane == 0) { lds[wv] = sum; lds[8 + wv] = sum2; }
    __syncthreads();
    if (t == 0) {
        float S1 = lds[0] + lds[1] + lds[2] + lds[3];
        float S2 = lds[8] + lds[9] + lds[10] + lds[11];
        float m = S1 * (1.0f / (float)HWN);
        float var = fmaf(-m, m, S2 * (1.0f / (float)HWN));
        float istd = rsqrtf(var + EPS_INST);
        float A = istd * (s0p + 1.0f);
        lds[12] = A;
        lds[13] = fmaf(-m, A, s1p);
    }
    __syncthreads();
    const float A = lds[12];
    const float Bs = lds[13];

    vf4* o4 = (vf4*)out + (size_t)(b * CC + c) * HW4;
#pragma unroll
    for (int i = 0; i < 4; ++i) {
        const int qq = t + 256 * i;
        float4 zz = zv[i];
        vf4 o;
        o.x = fmaf(zz.x, A, Bs);
        o.y = fmaf(zz.y, A, Bs);
        o.z = fmaf(zz.z, A, Bs);
        o.w = fmaf(zz.w, A, Bs);
        __builtin_nontemporal_store(o, o4 + qq);
    }
}

// ---------------------------------------------------------------------------
extern "C" void kernel_launch(void* const* d_in, const int* in_sizes, int n_in,
                              void* d_out, int out_size, void* d_ws, size_t ws_size,
                              hipStream_t stream) {
    const float* x      = (const float*)d_in[0];  // [16,512,64,64]
    const float* noise  = (const float*)d_in[1];  // [16,1,64,64]
    const float* style  = (const float*)d_in[2];  // [16,512]
    const float* nw     = (const float*)d_in[3];  // [512]
    const float* lin_W  = (const float*)d_in[4];  // [512,1024]
    const float* lin_b  = (const float*)d_in[5];  // [1024]
    float* out = (float*)d_out;
    float* ws  = (float*)d_ws;

    float* sp        = ws;                          // 16*4*1024 = 65536 floats
    float* rbuf      = ws + 65536;                  // 16*4096  = 65536 floats
    unsigned* cnt    = (unsigned*)(ws + 131072);    // 16 counters
    unsigned* tick   = cnt + 16;                    // 1 ticket counter

    k0_init<<<1, 64, 0, stream>>>(cnt);
    fused<<<NPROD + NCONS, 256, 0, stream>>>(
        x, noise, nw, style, lin_W, lin_b, sp, rbuf, cnt, tick, out);
}

// Round 2
// 258.245 us; speedup vs baseline: 6.5080x; 6.5080x over previous
//
#include <hip/hip_runtime.h>

// SGLayerEpilogue: noise-add -> LeakyReLU(0.2) -> PixelNorm(over C) ->
// InstanceNorm(over HW) -> StyleMod(linear scale/shift)
// B=16, C=512, H=W=64, S=512. All fp32.
//
// Two-kernel structure (single-launch fusion REGRESSED 6.5x in round 1:
// 2M spinning threads on device-scope atomics starved the producers).

#define BB 16
#define CC 512
#define HWN 4096          // H*W
#define HW4 1024          // HW / 4 (float4 units)
#define NSTYLE 256        // style partial blocks: 16 b x 4 jgroup x 4 kchunk
#define NPIXB 256         // pixel blocks: 16 b x 16 chunks of 256 px

#define EPS_PIXEL 1e-8f
#define EPS_INST 1e-5f

typedef float vf4 __attribute__((ext_vector_type(4)));

// ---------------------------------------------------------------------------
// K1: merged grid.
//   blocks [0, NSTYLE): style-GEMM partials, K split 4 ways.
//       sp[(b*4 + z)*1024 + j] = (z==0 ? lin_b[j] : 0) + sum_{k in chunk z}
//                                 style[b,k] * lin_W[k,j]
//   blocks [NSTYLE, NSTYLE + NPIXB): per-pixel sum of y^2 over ALL channels.
//       Block owns 256 pixels (64 float4 quads); thread t: quad = t&63,
//       channel group = t>>6 (128 channels each). Wave loads are 64 lanes x
//       16 B = 1 KB contiguous (vs 256 B in the scalar version).
//       LDS-fold the 4 groups -> rbuf[b,hw] = rsqrt(mean_c(y^2)+eps), float4.
// Style blocks come FIRST so their latency-bound FMA chains hide under the
// memory-bound x streaming of the pixel blocks.
// ---------------------------------------------------------------------------
__global__ __launch_bounds__(256) void k1_stats(
        const float* __restrict__ x,
        const float* __restrict__ noise,
        const float* __restrict__ nw,
        const float* __restrict__ style,
        const float* __restrict__ lin_W,
        const float* __restrict__ lin_b,
        float* __restrict__ rbuf,
        float* __restrict__ sp) {
    const int bid = blockIdx.x;
    const int t = threadIdx.x;

    if (bid < NSTYLE) {
        // ---- style GEMM partial ----
        const int b  = bid >> 4;        // / 16
        const int jg = (bid >> 2) & 3;  // j group (256 cols each)
        const int z  = bid & 3;         // k chunk (128 rows each)
        const int j  = jg * 256 + t;
        __shared__ float ssty[128];
        if (t < 128) ssty[t] = style[b * 512 + z * 128 + t];
        __syncthreads();
        float acc = (z == 0) ? lin_b[j] : 0.0f;
        const float* Wp = lin_W + (size_t)(z * 128) * 1024 + j;
#pragma unroll 8
        for (int k = 0; k < 128; ++k)
            acc = fmaf(ssty[k], Wp[(size_t)k * 1024], acc);
        sp[(size_t)(b * 4 + z) * 1024 + j] = acc;
        return;
    }

    // ---- per-pixel channel reduction (float4 over pixels) ----
    const int pb    = bid - NSTYLE;   // 0 .. NPIXB-1
    const int b     = pb >> 4;        // / 16
    const int chunk = pb & 15;        // 256-px chunk
    const int p4    = t & 63;         // pixel quad within chunk
    const int g     = t >> 6;         // channel group (128 ch each)
    const int base4 = chunk * 64 + p4;  // float4 index in the 1024-quad plane

    __shared__ float snw[CC];
    __shared__ float4 red[256];
    snw[t] = nw[t];
    snw[t + 256] = nw[t + 256];
    __syncthreads();

    const float4* n4 = (const float4*)noise + (size_t)b * HW4;
    const float4 nz = n4[base4];
    const float4* xp = (const float4*)x
                     + (size_t)(b * CC + g * 128) * HW4 + base4;

    float4 acc = {0.f, 0.f, 0.f, 0.f};
#pragma unroll 8
    for (int k = 0; k < 128; ++k) {
        float4 v = xp[(size_t)k * HW4];
        float w = snw[g * 128 + k];
        float y0 = fmaf(w, nz.x, v.x); y0 = fmaxf(y0, 0.2f * y0);
        float y1 = fmaf(w, nz.y, v.y); y1 = fmaxf(y1, 0.2f * y1);
        float y2 = fmaf(w, nz.z, v.z); y2 = fmaxf(y2, 0.2f * y2);
        float y3 = fmaf(w, nz.w, v.w); y3 = fmaxf(y3, 0.2f * y3);
        acc.x = fmaf(y0, y0, acc.x);
        acc.y = fmaf(y1, y1, acc.y);
        acc.z = fmaf(y2, y2, acc.z);
        acc.w = fmaf(y3, y3, acc.w);
    }

    red[t] = acc;
    __syncthreads();
    if (t < 64) {
        float4 a = red[t], b1 = red[t + 64], c1 = red[t + 128], d = red[t + 192];
        float4 s;
        s.x = (a.x + b1.x) + (c1.x + d.x);
        s.y = (a.y + b1.y) + (c1.y + d.y);
        s.z = (a.z + b1.z) + (c1.z + d.z);
        s.w = (a.w + b1.w) + (c1.w + d.w);
        float4 r;
        r.x = rsqrtf(fmaf(s.x, 1.0f / (float)CC, EPS_PIXEL));
        r.y = rsqrtf(fmaf(s.y, 1.0f / (float)CC, EPS_PIXEL));
        r.z = rsqrtf(fmaf(s.z, 1.0f / (float)CC, EPS_PIXEL));
        r.w = rsqrtf(fmaf(s.w, 1.0f / (float)CC, EPS_PIXEL));
        ((float4*)rbuf)[(size_t)b * HW4 + chunk * 64 + t] = r;
    }
}

// ---------------------------------------------------------------------------
// K2: fused InstanceNorm + StyleMod.
// One block per (b,c) plane (4096 px). z = y*r kept in registers across the
// stats reduction; out = z*A + Bias with A = istd*(s0+1), Bias = s1 - m*A.
// Style scale/shift folded from the 4 K-chunk partials by the block leader.
// out written with nontemporal stores so the 134 MB stream doesn't evict x
// (which this kernel is concurrently re-reading) from the Infinity Cache.
// ---------------------------------------------------------------------------
__global__ __launch_bounds__(256) void fused_apply(
        const float* __restrict__ x,
        const float* __restrict__ noise,
        const float* __restrict__ nw,
        const float* __restrict__ rbuf,
        const float* __restrict__ sp,
        float* __restrict__ out) {
    const int bid = blockIdx.x;     // 0 .. B*C-1
    const int b = bid >> 9;
    const int c = bid & 511;
    const int t = threadIdx.x;
    const float w = nw[c];

    // Leader prefetches style partials early to hide L2 latency.
    float s0p = 0.f, s1p = 0.f;
    if (t == 0) {
#pragma unroll
        for (int z = 0; z < 4; ++z) {
            s0p += sp[(size_t)(b * 4 + z) * 1024 + c];
            s1p += sp[(size_t)(b * 4 + z) * 1024 + 512 + c];
        }
    }

    const float4* x4 = (const float4*)x + (size_t)(b * CC + c) * HW4;
    const float4* n4 = (const float4*)noise + (size_t)b * HW4;
    const float4* r4 = (const float4*)rbuf + (size_t)b * HW4;

    float4 zv[4];
    float sum = 0.f, sum2 = 0.f;
#pragma unroll
    for (int i = 0; i < 4; ++i) {
        const int q = t + 256 * i;
        float4 v = x4[q];
        float4 nz = n4[q];
        float4 rr = r4[q];
        float y0 = fmaf(w, nz.x, v.x); y0 = fmaxf(y0, 0.2f * y0);
        float y1 = fmaf(w, nz.y, v.y); y1 = fmaxf(y1, 0.2f * y1);
        float y2 = fmaf(w, nz.z, v.z); y2 = fmaxf(y2, 0.2f * y2);
        float y3 = fmaf(w, nz.w, v.w); y3 = fmaxf(y3, 0.2f * y3);
        float4 zz;
        zz.x = y0 * rr.x; zz.y = y1 * rr.y; zz.z = y2 * rr.z; zz.w = y3 * rr.w;
        zv[i] = zz;
        sum  += zz.x + zz.y + zz.z + zz.w;
        sum2 = fmaf(zz.x, zz.x, sum2);
        sum2 = fmaf(zz.y, zz.y, sum2);
        sum2 = fmaf(zz.z, zz.z, sum2);
        sum2 = fmaf(zz.w, zz.w, sum2);
    }

    // block reduce (4 waves of 64)
    __shared__ float lds[16];
#pragma unroll
    for (int off = 32; off > 0; off >>= 1) {
        sum  += __shfl_down(sum, off, 64);
        sum2 += __shfl_down(sum2, off, 64);
    }
    const int lane = t & 63, wv = t >> 6;
    if (lane == 0) { lds[wv] = sum; lds[8 + wv] = sum2; }
    __syncthreads();
    if (t == 0) {
        float S1 = lds[0] + lds[1] + lds[2] + lds[3];
        float S2 = lds[8] + lds[9] + lds[10] + lds[11];
        float m = S1 * (1.0f / (float)HWN);
        float var = fmaf(-m, m, S2 * (1.0f / (float)HWN));
        float istd = rsqrtf(var + EPS_INST);
        float A = istd * (s0p + 1.0f);
        lds[12] = A;
        lds[13] = fmaf(-m, A, s1p);
    }
    __syncthreads();
    const float A = lds[12];
    const float Bs = lds[13];

    vf4* o4 = (vf4*)out + (size_t)(b * CC + c) * HW4;
#pragma unroll
    for (int i = 0; i < 4; ++i) {
        const int q = t + 256 * i;
        float4 zz = zv[i];
        vf4 o;
        o.x = fmaf(zz.x, A, Bs);
        o.y = fmaf(zz.y, A, Bs);
        o.z = fmaf(zz.z, A, Bs);
        o.w = fmaf(zz.w, A, Bs);
        __builtin_nontemporal_store(o, o4 + q);
    }
}

// ---------------------------------------------------------------------------
extern "C" void kernel_launch(void* const* d_in, const int* in_sizes, int n_in,
                              void* d_out, int out_size, void* d_ws, size_t ws_size,
                              hipStream_t stream) {
    const float* x      = (const float*)d_in[0];  // [16,512,64,64]
    const float* noise  = (const float*)d_in[1];  // [16,1,64,64]
    const float* style  = (const float*)d_in[2];  // [16,512]
    const float* nw     = (const float*)d_in[3];  // [512]
    const float* lin_W  = (const float*)d_in[4];  // [512,1024]
    const float* lin_b  = (const float*)d_in[5];  // [1024]
    float* out = (float*)d_out;
    float* ws  = (float*)d_ws;

    float* sp   = ws;             // style partials: 16*4*1024 = 65536 floats
    float* rbuf = ws + 65536;     // 16*4096 = 65536 floats

    k1_stats<<<NSTYLE + NPIXB, 256, 0, stream>>>(
        x, noise, nw, style, lin_W, lin_b, rbuf, sp);
    fused_apply<<<BB * CC, 256, 0, stream>>>(x, noise, nw, rbuf, sp, out);
}